// Round 7
// baseline (310.313 us; speedup 1.0000x reference)
//
#include <hip/hip_runtime.h>
#include <hip/hip_bf16.h>
#include <stdint.h>

typedef float f32x4 __attribute__((ext_vector_type(4)));
typedef float f32x16 __attribute__((ext_vector_type(16)));
typedef short s16x8 __attribute__((ext_vector_type(8)));
typedef unsigned int u32x2 __attribute__((ext_vector_type(2)));
typedef unsigned int u32x4 __attribute__((ext_vector_type(4)));

#define MDIM 8192
#define NDIM 4096
#define KDIM 4096
#define NKT  64   // K-tiles of 64

__device__ __forceinline__ unsigned pkbf(float lo, float hi) {
  unsigned short l = __builtin_bit_cast(unsigned short, __float2bfloat16(lo));
  unsigned short h = __builtin_bit_cast(unsigned short, __float2bfloat16(hi));
  return ((unsigned)h << 16) | (unsigned)l;
}

__device__ __forceinline__ void gload16(const void* g, void* l) {
  __builtin_amdgcn_global_load_lds((const __attribute__((address_space(1))) int*)g,
                                   (__attribute__((address_space(3))) int*)l, 16, 0, 0);
}

// Convert f32 row-major [rows][4096] -> bf16 32x32x16-MFMA fragment layout.
// Per (row-tile rt of 256, K-tile kt of 64): 32 KB = [h:2][ks2:2][f:8] x 1KB.
// Frag (h,ks2,f): rows f*32..+31, k = kt*64+h*32+ks2*16..+15; slot lane*16B
// holds row=lane&31, k-half=(lane>>5)*8, 8 contiguous bf16 (A/B operand
// layout of mfma_f32_32x32x16_bf16). ds_read_b128 = lane*16 conflict-free.
__global__ __launch_bounds__(256) void conv_tile(
    const float* __restrict__ X, const float* __restrict__ W,
    s16x8* __restrict__ wsA, s16x8* __restrict__ wsB) {
  __shared__ char lds[32768];
  const int b = blockIdx.x;
  const int tid = threadIdx.x;
  const float* src;
  s16x8* dst;
  int bi;
  if (b < 32 * NKT) { src = X; dst = wsA; bi = b; }
  else              { src = W; dst = wsB; bi = b - 32 * NKT; }
  const int rt = bi >> 6;
  const int kt = bi & 63;
  const int fr = tid >> 4;        // row sub-index (0..15)
  const int c4 = (tid & 15) * 4;  // k offset (f32 units) within K-tile
  const int h = c4 >> 5;
  const int ks2 = (c4 >> 4) & 1;
  const int lh = (c4 & 15) >> 3;  // k-half within 16-step
  const int e2 = (c4 & 7) * 2;    // byte offset of first elem
  #pragma unroll
  for (int f = 0; f < 16; ++f) {
    const int row = f * 16 + fr;
    f32x4 v = *(const f32x4*)(src + ((size_t)rt * 256 + row) * KDIM + kt * 64 + c4);
    u32x2 p = { pkbf(v[0], v[1]), pkbf(v[2], v[3]) };
    const int frag = (h * 2 + ks2) * 8 + (f >> 1);
    const int lane = lh * 32 + (f & 1) * 16 + fr;
    *(u32x2*)(lds + frag * 1024 + lane * 16 + e2) = p;
  }
  __syncthreads();
  const size_t ob = (size_t)bi * 2048;
  #pragma unroll
  for (int i = 0; i < 8; ++i)
    dst[ob + i * 256 + tid] = *(const s16x8*)(lds + (i * 256 + tid) * 16);
}

// 256x256x4096 bf16 GEMM, 32x32x16 MFMA, 8 single-barrier phases per 2
// K-tiles (reads+stage before barrier; no closing barrier -> waves desync
// within a phase and LDS time hides under sibling MFMA), fused group epilogue.
__global__ __launch_bounds__(512, 2) void gemm256(
    const s16x8* __restrict__ wsA, const s16x8* __restrict__ wsB,
    const float* __restrict__ bias, const float* __restrict__ Wg,
    const float* __restrict__ bg, float* __restrict__ out) {
  extern __shared__ char smem[];
  const int tid = threadIdx.x;
  const int lane = tid & 63;
  const int wid = tid >> 6;      // 0..7
  const int wr = wid >> 2;       // 0..1  (wave row: 128 rows)
  const int wc = wid & 3;        // 0..3  (wave col: 64 cols)
  const int c32 = lane & 31;
  const int q5 = lane >> 5;

  const int bid = blockIdx.x;
  const int swz = (bid & 7) * 64 + (bid >> 3);   // XCD-bijective (512 % 8 == 0)
  const int bm = swz >> 4;       // 0..31
  const int bn = swz & 15;       // 0..15

  const size_t aBase = (size_t)bm * NKT * 2048;  // 16B-slot units
  const size_t bBase = (size_t)bn * NKT * 2048;

  auto stage = [&](int kt, int db, int isB, int h) {
    const s16x8* s = (isB ? wsB + bBase : wsA + aBase)
                     + (size_t)kt * 2048 + h * 1024 + wid * 128 + lane;
    char* d = smem + isB * 65536 + db * 32768 + h * 16384 + wid * 2048;
    gload16(s, d);
    gload16(s + 64, d + 1024);
  };

  const char* aRd = smem + wr * 4096 + lane * 16;            // A frags f=wr*4+m
  const char* bRd = smem + 65536 + wc * 2048 + lane * 16;    // B frags f=wc*2+n

  f32x16 acc[4][2];
  #pragma unroll
  for (int m = 0; m < 4; ++m)
    #pragma unroll
    for (int n = 0; n < 2; ++n) acc[m][n] = (f32x16)0.0f;

  s16x8 af[4], bfr[2];

  // Phase (DB,H,KS2): stage one {A|B} half; read 4 A + 2 B frags; vmcnt(4)
  // at P4/P8 only (6 stages in flight); ONE barrier; lgkm(0); 8 MFMA.
  // Stage schedule (re-derived for the read-both-ops-every-phase map):
  // P1/P2: (u0+1).{A,B}.h1->db1; P3..P6: (u0+2) full->db0; P7/P8:
  // (u0+3).{A,B}.h0->db1. Landing: P8.vmcnt(4) covers P3..P6 (db0, read
  // nP1..nP4); P4.vmcnt(4) covers prevP7,P8+P1,P2 (db1, read P5..P8).
#define SP(DB, H, KS2, SKT, SDB, SOP, SH, DOVM)                                \
  {                                                                            \
    stage(SKT, SDB, SOP, SH);                                                  \
    _Pragma("unroll")                                                          \
    for (int n = 0; n < 2; ++n)                                                \
      bfr[n] = *(const s16x8*)(bRd + (DB)*32768 + (H)*16384 + (KS2)*8192 + n * 1024); \
    _Pragma("unroll")                                                          \
    for (int m = 0; m < 4; ++m)                                                \
      af[m] = *(const s16x8*)(aRd + (DB)*32768 + (H)*16384 + (KS2)*8192 + m * 1024);  \
    if (DOVM) asm volatile("s_waitcnt vmcnt(4)" ::: "memory");                 \
    __builtin_amdgcn_s_barrier();                                              \
    asm volatile("s_waitcnt lgkmcnt(0)" ::: "memory");                         \
    __builtin_amdgcn_s_setprio(1);                                             \
    _Pragma("unroll")                                                          \
    for (int m = 0; m < 4; ++m) {                                              \
      _Pragma("unroll")                                                        \
      for (int n = 0; n < 2; ++n)                                              \
        acc[m][n] = __builtin_amdgcn_mfma_f32_32x32x16_bf16(                   \
            af[m], bfr[n], acc[m][n], 0, 0, 0);                                \
    }                                                                          \
    __builtin_amdgcn_s_setprio(0);                                             \
  }

  // Prologue: t0 full + t1.h0 (6 stages); vmcnt(4) -> t0 (s1..s4) landed.
  stage(0, 0, 0, 0); stage(0, 0, 1, 0);
  stage(0, 0, 0, 1); stage(0, 0, 1, 1);
  stage(1, 1, 0, 0); stage(1, 1, 1, 0);
  asm volatile("s_waitcnt vmcnt(4)" ::: "memory");
  __builtin_amdgcn_s_barrier();

  #pragma clang loop unroll(disable)
  for (int it = 0; it < 32; ++it) {
    const int u0 = 2 * it;
    const int k1 = u0 + 1;                        // <= 63 always
    const int k2 = (u0 + 2 < NKT) ? u0 + 2 : NKT - 1;
    const int k3 = (u0 + 3 < NKT) ? u0 + 3 : NKT - 1;
    SP(0, 0, 0, k1, 1, 0, 1, 0)   // P1: (u0+1).A.h1 -> db1
    SP(0, 0, 1, k1, 1, 1, 1, 0)   // P2: (u0+1).B.h1 -> db1
    SP(0, 1, 0, k2, 0, 0, 0, 0)   // P3: (u0+2).A.h0 -> db0
    SP(0, 1, 1, k2, 0, 1, 0, 1)   // P4: (u0+2).B.h0 -> db0, vmcnt(4)
    SP(1, 0, 0, k2, 0, 0, 1, 0)   // P5: (u0+2).A.h1 -> db0
    SP(1, 0, 1, k2, 0, 1, 1, 0)   // P6: (u0+2).B.h1 -> db0
    SP(1, 1, 0, k3, 1, 0, 0, 0)   // P7: (u0+3).A.h0 -> db1
    SP(1, 1, 1, k3, 1, 1, 0, 1)   // P8: (u0+3).B.h0 -> db1, vmcnt(4)
  }
#undef SP

  // ---- drain, then fused group-linear epilogue ----
  asm volatile("s_waitcnt vmcnt(0)" ::: "memory");
  asm volatile("s_waitcnt lgkmcnt(0)" ::: "memory");
  __builtin_amdgcn_s_barrier();

  float bv[2];
  #pragma unroll
  for (int n = 0; n < 2; ++n) bv[n] = bias[bn * 256 + wc * 64 + n * 32 + c32];

  // y = acc + bias -> bf16 into sY fragment layout [Mf:8][Kc:16] x 1KB,
  // element (row,col): Mf=row>>5, Kc=col>>4, slot=((col>>3)&1)*32+(row&31),
  // byte = slot*16 + (col&7)*2.  (A-operand layout for the grouped GEMM.)
  {
    const int e2 = (c32 & 7) * 2;
    const int lh = (c32 >> 3) & 1;
    #pragma unroll
    for (int m = 0; m < 4; ++m) {
      const int Mf = wr * 4 + m;
      #pragma unroll
      for (int n = 0; n < 2; ++n) {
        const int Kc = wc * 4 + n * 2 + (c32 >> 4);
        char* base = smem + (Mf * 16 + Kc) * 1024 + lh * 512 + e2;
        #pragma unroll
        for (int r = 0; r < 16; ++r) {
          const int rl = (r & 3) + 8 * (r >> 2) + 4 * q5;
          const float y = acc[m][n][r] + bv[n];
          *(unsigned short*)(base + rl * 16) =
              __builtin_bit_cast(unsigned short, __float2bfloat16(y));
        }
      }
    }
  }
  asm volatile("s_waitcnt lgkmcnt(0)" ::: "memory");
  __builtin_amdgcn_s_barrier();

  // out_g = sY_g @ Wg[g]^T + bg ; wave (wr,wc): 128x64 out sub-tile,
  // K = its group's 128 y-cols (Kc = (wc>>1)*8 + ks). Wg direct from global
  // (L2-resident), converted in-reg to 32x32 B-fragments.
  const int g = bn * 2 + (wc >> 1);
  const float* wgb = Wg + (size_t)g * 16384;
  f32x16 acc2[4][2];
  #pragma unroll
  for (int m = 0; m < 4; ++m)
    #pragma unroll
    for (int n = 0; n < 2; ++n) acc2[m][n] = (f32x16)0.0f;

  #pragma unroll
  for (int ks = 0; ks < 8; ++ks) {
    const int Kc = (wc >> 1) * 8 + ks;
    s16x8 af2[4];
    #pragma unroll
    for (int m = 0; m < 4; ++m)
      af2[m] = *(const s16x8*)(smem + ((wr * 4 + m) * 16 + Kc) * 1024 + lane * 16);
    #pragma unroll
    for (int n = 0; n < 2; ++n) {
      const int ocl = (wc & 1) * 64 + n * 32 + c32;    // out col within group
      const float* wp = wgb + ocl * 128 + ks * 16 + q5 * 8;
      f32x4 w0 = *(const f32x4*)wp;
      f32x4 w1 = *(const f32x4*)(wp + 4);
      u32x4 pw = { pkbf(w0[0], w0[1]), pkbf(w0[2], w0[3]),
                   pkbf(w1[0], w1[1]), pkbf(w1[2], w1[3]) };
      const s16x8 bfw = __builtin_bit_cast(s16x8, pw);
      #pragma unroll
      for (int m = 0; m < 4; ++m)
        acc2[m][n] = __builtin_amdgcn_mfma_f32_32x32x16_bf16(af2[m], bfw, acc2[m][n], 0, 0, 0);
    }
  }

  float bgv[2];
  #pragma unroll
  for (int n = 0; n < 2; ++n) bgv[n] = bg[bn * 256 + wc * 64 + n * 32 + c32];

  #pragma unroll
  for (int m = 0; m < 4; ++m) {
    #pragma unroll
    for (int n = 0; n < 2; ++n) {
      const int col = bn * 256 + wc * 64 + n * 32 + c32;
      #pragma unroll
      for (int r = 0; r < 16; ++r) {
        const size_t row = (size_t)bm * 256 + wr * 128 + m * 32
                         + (r & 3) + 8 * (r >> 2) + 4 * q5;
        out[row * NDIM + col] = acc2[m][n][r] + bgv[n];
      }
    }
  }
}

extern "C" void kernel_launch(void* const* d_in, const int* in_sizes, int n_in,
                              void* d_out, int out_size, void* d_ws, size_t ws_size,
                              hipStream_t stream) {
  const float* X    = (const float*)d_in[0];
  const float* W    = (const float*)d_in[1];
  const float* bias = (const float*)d_in[2];
  const float* Wg   = (const float*)d_in[3];
  const float* bg   = (const float*)d_in[4];
  float* out = (float*)d_out;

  s16x8* wsA = (s16x8*)d_ws;                       // 64 MB
  s16x8* wsB = wsA + ((size_t)MDIM * KDIM / 8);    // 32 MB

  hipFuncSetAttribute(reinterpret_cast<const void*>(gemm256),
                      hipFuncAttributeMaxDynamicSharedMemorySize, 131072);

  conv_tile<<<dim3(3072), dim3(256), 0, stream>>>(X, W, wsA, wsB);
  gemm256<<<dim3(512), dim3(512), 131072, stream>>>(wsA, wsB, bias, Wg, bg, out);
}